// Round 7
// baseline (781.392 us; speedup 1.0000x reference)
//
#include <hip/hip_runtime.h>

#define NN 100000
#define NE 1600000
#define NLAYERS 5
#define GIN_EPSF 0.5f
#define BN_EPSF 1e-5f
#define NB 391                 // ceil(NN/256) buckets of 256 nodes
#define CAPR 4608              // raw edges capacity per bucket (mean 4096 + 8 sigma)
#define GRID_L 3072
#define NWAVES (GRID_L * 4)
#define CAPQ 80                // staged idx quads per wave (chunk ~36 + headroom)
#define CAPN 80                // staged work entries per wave

typedef unsigned short bfu;
typedef unsigned short u16x4 __attribute__((ext_vector_type(4)));
typedef float f32x4 __attribute__((ext_vector_type(4)));

__device__ inline float bf2f(bfu u) {
    unsigned x = ((unsigned)u) << 16;
    return __builtin_bit_cast(float, x);
}
__device__ inline bfu f2bf(float f) {
    unsigned x = __builtin_bit_cast(unsigned, f);
    unsigned r = (x + 0x7FFF + ((x >> 16) & 1)) >> 16;
    return (bfu)r;
}
__device__ inline f32x4 cvt4(u16x4 v) {
    f32x4 r;
    r.x = bf2f(v.x); r.y = bf2f(v.y); r.z = bf2f(v.z); r.w = bf2f(v.w);
    return r;
}

// tabs layout (ints): [0]=Kc [1]=TotQ [2+k]=cls_q [66+k]=cls_nodeBase
// [130+k]=cls_quadBase (sentinel at Kc) [200+q]=byq_nodeBase [264+q]=byq_quadBase

// ---------------- embedding gather -> bf16 h0 (+ zero dummy row NN) ----------------
__global__ __launch_bounds__(256) void k_embed(const int* __restrict__ x,
                                               const float* __restrict__ table,
                                               bfu* __restrict__ P) {
    int idx = blockIdx.x * 256 + threadIdx.x;
    if (idx >= (NN + 1) * 16) return;
    int i = idx >> 4, fq = idx & 15;
    u16x4 o = {0, 0, 0, 0};
    if (i < NN) {
        f32x4 v = *(const f32x4*)(table + x[2 * i] * 64 + fq * 4);
        o.x = f2bf(v.x); o.y = f2bf(v.y); o.z = f2bf(v.z); o.w = f2bf(v.w);
    }
    *(u16x4*)(P + (size_t)i * 64 + fq * 4) = o;
}

// ---------------- partition edges into fixed-capacity bucket windows ----------------
__global__ __launch_bounds__(256) void k_part(const int* __restrict__ src,
                                              const int* __restrict__ dst,
                                              int* __restrict__ bcnt,
                                              int* __restrict__ tmp) {
    __shared__ int h[NB];
    __shared__ int hb[NB];
    int t = threadIdx.x;
    for (int k = t; k < NB; k += 256) h[k] = 0;
    __syncthreads();
    int base = blockIdx.x * 2048;
    int v_[8], b_[8], r_[8];
#pragma unroll
    for (int u = 0; u < 8; ++u) {
        int e = base + u * 256 + t;
        if (e < NE) {
            int d = dst[e];
            b_[u] = d >> 8;
            v_[u] = src[e] | ((d & 255) << 20);
            r_[u] = atomicAdd(&h[b_[u]], 1);
        } else {
            b_[u] = -1;
        }
    }
    __syncthreads();
    for (int k = t; k < NB; k += 256)
        hb[k] = h[k] ? (k * CAPR + atomicAdd(&bcnt[k], h[k])) : 0;
    __syncthreads();
#pragma unroll
    for (int u = 0; u < 8; ++u) {
        if (b_[u] >= 0) tmp[hb[b_[u]] + r_[u]] = v_[u];
    }
}

// ---------------- per-bucket: degree count + per-bucket bin histogram ----------------
__global__ __launch_bounds__(256) void k_cnt(const int* __restrict__ tmp,
                                             const int* __restrict__ bcnt,
                                             int* __restrict__ pk,
                                             int* __restrict__ gbh) {
    __shared__ int cnt[256];
    __shared__ int lbh[64];
    int b = blockIdx.x, t = threadIdx.x;
    int n = bcnt[b];
    const int* w = tmp + (size_t)b * CAPR;
    cnt[t] = 0;
    if (t < 64) lbh[t] = 0;
    __syncthreads();
    for (int k = t; k < n; k += 256) atomicAdd(&cnt[w[k] >> 20], 1);
    __syncthreads();
    int node = b * 256 + t;
    int c = cnt[t];
    int pkv = 0;
    if (node < NN) {
        int nq = c ? ((c + 3) >> 2) : 1;     // zero-degree nodes get 1 quad of dummies
        int rl = atomicAdd(&lbh[nq], 1);
        pkv = c | (rl << 9) | (nq << 17);
    }
    pk[b * 256 + t] = pkv;
    __syncthreads();
    if (t < 64) gbh[b * 64 + t] = lbh[t];
}

// ---------------- global scan: per-bin bucket prefixes + class tables ----------------
__global__ void k_scan(const int* __restrict__ gbh, int* __restrict__ gBinBase,
                       int* __restrict__ tabs) {
    __shared__ int tot[64];
    int t = threadIdx.x;   // 64 threads, thread t owns bin t
    int run = 0;
    for (int b = 0; b < NB; ++b) {
        int v = gbh[b * 64 + t];
        gBinBase[b * 64 + t] = run;
        run += v;
    }
    tot[t] = run;
    __syncthreads();
    if (t == 0) {
        int K = 0, nb = 0;
        long qb = 0;
        for (int q = 63; q >= 1; --q) {      // descending degree
            int cN = tot[q];
            if (!cN) continue;
            tabs[2 + K] = q;
            tabs[66 + K] = nb;
            tabs[130 + K] = (int)qb;
            tabs[200 + q] = nb;
            tabs[264 + q] = (int)qb;
            nb += cN;
            qb += (long)cN * q;
            ++K;
        }
        tabs[130 + K] = (int)qb;             // sentinel
        tabs[0] = K;
        tabs[1] = (int)qb;                   // TotQ
    }
}

// ---------------- place: sorted work list + padded srcList ----------------
__global__ __launch_bounds__(256) void k_place(const int* __restrict__ tmp,
                                               const int* __restrict__ bcnt,
                                               const int* __restrict__ pk,
                                               const int* __restrict__ gBinBase,
                                               const int* __restrict__ tabs,
                                               int2* __restrict__ work,
                                               int* __restrict__ srcList) {
    __shared__ int cur[256];
    int b = blockIdx.x, t = threadIdx.x;
    int n = bcnt[b];
    const int* w = tmp + (size_t)b * CAPR;
    int node = b * 256 + t;
    int pkv = pk[b * 256 + t];
    if (node < NN) {
        int c = pkv & 511;
        int rl = (pkv >> 9) & 255;
        int nq = pkv >> 17;
        int rank = gBinBase[b * 64 + nq] + rl;           // rank within class
        int sp = tabs[200 + nq] + rank;                  // global sorted position
        int beg = (tabs[264 + nq] + rank * nq) * 4;
        work[sp] = make_int2(beg, node | (nq << 20));
        cur[t] = beg;
        for (int k = c; k < nq * 4; ++k) srcList[beg + k] = NN;   // dummy zero-row
    }
    __syncthreads();
    for (int k = t; k < n; k += 256) {
        int v = w[k];
        int pos = atomicAdd(&cur[v >> 20], 1);
        srcList[pos] = v & 0xFFFFF;
    }
}

// ---------------- chunk helpers over class tables ----------------
__device__ inline int rank_of_quad(long T, int Kc, int TotQ,
                                   const int* s_q, const int* s_nb, const int* s_qb) {
    if (T >= TotQ) return NN;
    int i = 0;
    for (int j = 1; j < Kc; ++j)
        if (T >= s_qb[j]) i = j;
    int q = s_q[i];
    return s_nb[i] + (int)((T - s_qb[i] + q - 1) / q);   // first rank starting at/after T
}
__device__ inline int quad_start(int rank, int Kc, int TotQ,
                                 const int* s_q, const int* s_nb, const int* s_qb) {
    if (rank >= NN) return TotQ;
    int i = 0;
    for (int j = 1; j < Kc; ++j)
        if (rank >= s_nb[j]) i = j;
    return s_qb[i] + (rank - s_nb[i]) * s_q[i];
}

// ---------------- fused layer: LDS-staged indices, VMEM FIFO holds only rows ----------------
__global__ __launch_bounds__(256, 6) void k_layer(
    const bfu* __restrict__ P, float* __restrict__ Q,
    const int2* __restrict__ work, const int* __restrict__ srcList,
    const int* __restrict__ tabs, float* __restrict__ sums) {
    __shared__ float ssum[64], ssq[64];
    __shared__ int s_q[64], s_nb[64], s_qb[65];
    __shared__ int4 widx[4][CAPQ];
    __shared__ int2 wwork[4][CAPN];
    int t = threadIdx.x;
    if (t < 64) {
        ssum[t] = 0.f; ssq[t] = 0.f;
        s_q[t] = tabs[2 + t];
        s_nb[t] = tabs[66 + t];
    }
    if (t < 65) s_qb[t] = tabs[130 + t];
    __syncthreads();
    int Kc = tabs[0], TotQ = tabs[1];
    int ws = t >> 6;
    int lane = t & 63;
    int wv = blockIdx.x * 4 + ws;
    long Ts = (long)wv * TotQ / NWAVES;
    long Te = (long)(wv + 1) * TotQ / NWAVES;
    int n0 = rank_of_quad(Ts, Kc, TotQ, s_q, s_nb, s_qb);
    int n1 = rank_of_quad(Te, Kc, TotQ, s_q, s_nb, s_qb);
    int qs0 = quad_start(n0, Kc, TotQ, s_q, s_nb, s_qb);
    int qs1 = quad_start(n1, Kc, TotQ, s_q, s_nb, s_qb);
    int spanQ = qs1 - qs0;
    int spanN = n1 - n0;
    // bulk-stage this wave's indices + work entries into LDS (coalesced)
    const int4* srcQ = (const int4*)srcList;
    for (int k = lane; k < spanQ && k < CAPQ; k += 64) widx[ws][k] = srcQ[qs0 + k];
    for (int k = lane; k < spanN && k < CAPN; k += 64) wwork[ws][k] = work[n0 + k];
    int grp = (t >> 4) & 3;               // 4 groups of 16 lanes
    int c = t & 15;                       // lane covers features 4c..4c+3
    f32x4 lsum = {0.f, 0.f, 0.f, 0.f};
    f32x4 lsq = {0.f, 0.f, 0.f, 0.f};
    for (int k = grp; k < spanN; k += 4) {
        int2 wk;
        if (k < CAPN) wk = wwork[ws][k]; else wk = work[n0 + k];
        int beg = wk.x;
        int node = wk.y & 0xFFFFF;
        int nq = wk.y >> 20;
        int qo = (beg >> 2) - qs0;
        u16x4 selfv = *(const u16x4*)(P + (size_t)node * 64 + c * 4);
        int4 s;
        if (qo < CAPQ) s = widx[ws][qo]; else s = *(const int4*)(srcList + beg);
        u16x4 a0 = *(const u16x4*)(P + (size_t)s.x * 64 + c * 4);
        u16x4 a1 = *(const u16x4*)(P + (size_t)s.y * 64 + c * 4);
        u16x4 a2 = *(const u16x4*)(P + (size_t)s.z * 64 + c * 4);
        u16x4 a3 = *(const u16x4*)(P + (size_t)s.w * 64 + c * 4);
        f32x4 r = cvt4(selfv) * GIN_EPSF;
        for (int q = 1; q < nq; ++q) {
            int qq = qo + q;
            int4 sn;
            if (qq < CAPQ) sn = widx[ws][qq]; else sn = *(const int4*)(srcList + beg + 4 * q);
            u16x4 b0 = *(const u16x4*)(P + (size_t)sn.x * 64 + c * 4);
            u16x4 b1 = *(const u16x4*)(P + (size_t)sn.y * 64 + c * 4);
            u16x4 b2 = *(const u16x4*)(P + (size_t)sn.z * 64 + c * 4);
            u16x4 b3 = *(const u16x4*)(P + (size_t)sn.w * 64 + c * 4);
            r += (cvt4(a0) + cvt4(a1)) + (cvt4(a2) + cvt4(a3));
            a0 = b0; a1 = b1; a2 = b2; a3 = b3;
        }
        r += (cvt4(a0) + cvt4(a1)) + (cvt4(a2) + cvt4(a3));
        *(f32x4*)(Q + (size_t)node * 64 + c * 4) = r;
        lsum += r;
        lsq += r * r;
    }
    atomicAdd(&ssum[c * 4 + 0], lsum.x);
    atomicAdd(&ssum[c * 4 + 1], lsum.y);
    atomicAdd(&ssum[c * 4 + 2], lsum.z);
    atomicAdd(&ssum[c * 4 + 3], lsum.w);
    atomicAdd(&ssq[c * 4 + 0], lsq.x);
    atomicAdd(&ssq[c * 4 + 1], lsq.y);
    atomicAdd(&ssq[c * 4 + 2], lsq.z);
    atomicAdd(&ssq[c * 4 + 3], lsq.w);
    __syncthreads();
    if (t < 64) {
        atomicAdd(&sums[t], ssum[t]);
        atomicAdd(&sums[64 + t], ssq[t]);
    }
}

// ---------------- normalize agg -> bf16 h (params from sums inline) ----------------
__global__ __launch_bounds__(256) void k_norm(const float* __restrict__ Q,
                                              const float* __restrict__ sums,
                                              bfu* __restrict__ P) {
    __shared__ float prm[128];
    int t = threadIdx.x;
    if (t < 64) {
        float s = sums[t], sq = sums[64 + t];
        float mean = s / (float)NN;
        float var = fmaxf(sq / (float)NN - mean * mean, 0.f);
        prm[t] = rsqrtf(var + BN_EPSF);
        prm[64 + t] = mean;
    }
    __syncthreads();
    int idx = blockIdx.x * 256 + t;
    if (idx >= (NN + 1) * 16) return;
    int i = idx >> 4, fq = idx & 15;
    u16x4 o = {0, 0, 0, 0};
    if (i < NN) {
        f32x4 v = *(const f32x4*)(Q + (size_t)i * 64 + fq * 4);
        o.x = f2bf((v.x - prm[64 + fq * 4 + 0]) * prm[fq * 4 + 0]);
        o.y = f2bf((v.y - prm[64 + fq * 4 + 1]) * prm[fq * 4 + 1]);
        o.z = f2bf((v.z - prm[64 + fq * 4 + 2]) * prm[fq * 4 + 2]);
        o.w = f2bf((v.w - prm[64 + fq * 4 + 3]) * prm[fq * 4 + 3]);
    }
    *(u16x4*)(P + (size_t)i * 64 + fq * 4) = o;
}

// ---------------- final normalize -> fp32 out ----------------
__global__ __launch_bounds__(256) void k_final(const float* __restrict__ Q,
                                               const float* __restrict__ sums,
                                               float* __restrict__ out) {
    __shared__ float prm[128];
    int t = threadIdx.x;
    if (t < 64) {
        float s = sums[t], sq = sums[64 + t];
        float mean = s / (float)NN;
        float var = fmaxf(sq / (float)NN - mean * mean, 0.f);
        prm[t] = rsqrtf(var + BN_EPSF);
        prm[64 + t] = mean;
    }
    __syncthreads();
    int idx = blockIdx.x * 256 + t;
    if (idx >= NN * 16) return;
    int i = idx >> 4, fq = idx & 15;
    f32x4 v = *(const f32x4*)(Q + (size_t)i * 64 + fq * 4);
    f32x4 o;
    o.x = (v.x - prm[64 + fq * 4 + 0]) * prm[fq * 4 + 0];
    o.y = (v.y - prm[64 + fq * 4 + 1]) * prm[fq * 4 + 1];
    o.z = (v.z - prm[64 + fq * 4 + 2]) * prm[fq * 4 + 2];
    o.w = (v.w - prm[64 + fq * 4 + 3]) * prm[fq * 4 + 3];
    *(f32x4*)(out + (size_t)i * 64 + fq * 4) = o;
}

extern "C" void kernel_launch(void* const* d_in, const int* in_sizes, int n_in,
                              void* d_out, int out_size, void* d_ws, size_t ws_size,
                              hipStream_t stream) {
    const int* x = (const int*)d_in[0];          // (NN,2)
    const int* ei = (const int*)d_in[1];         // (2,NE)
    const float* table = (const float*)d_in[2];  // (120,64)
    const int* src = ei;
    const int* dst = ei + NE;
    float* out = (float*)d_out;

    // workspace carve-up (~55 MB)
    bfu* P = (bfu*)d_ws;                                   // (NN+1)*64 bf16
    float* Q = (float*)(P + (size_t)(NN + 1) * 64);        // NN*64 f32
    int* srcList = (int*)(Q + (size_t)NN * 64);            // NE + 4*NN
    int* tmp = srcList + (NE + 4 * NN);                    // NB*CAPR
    int2* work = (int2*)(tmp + (size_t)NB * CAPR);         // NN int2
    int* pk = (int*)(work + NN);                           // NB*256
    int* gBinBase = pk + NB * 256;                         // NB*64
    int* gbh = gBinBase + NB * 64;                         // NB*64
    int* bcnt = gbh + NB * 64;                             // NB
    float* sums = (float*)(bcnt + NB);                     // 5*128
    int* tabs = (int*)(sums + NLAYERS * 128);              // 512

    // zero bcnt + all sums slices in one memset
    hipMemsetAsync(bcnt, 0, (NB + NLAYERS * 128) * sizeof(int), stream);

    k_embed<<<((NN + 1) * 16 + 255) / 256, 256, 0, stream>>>(x, table, P);

    // CSR build: bucket partition -> global degree sort -> padded placement
    const int NPB = (NE + 2047) / 2048;  // 782
    k_part<<<NPB, 256, 0, stream>>>(src, dst, bcnt, tmp);
    k_cnt<<<NB, 256, 0, stream>>>(tmp, bcnt, pk, gbh);
    k_scan<<<1, 64, 0, stream>>>(gbh, gBinBase, tabs);
    k_place<<<NB, 256, 0, stream>>>(tmp, bcnt, pk, gBinBase, tabs, work, srcList);

    // 5 layers
    for (int L = 0; L < NLAYERS; ++L) {
        float* sL = sums + L * 128;
        k_layer<<<GRID_L, 256, 0, stream>>>(P, Q, work, srcList, tabs, sL);
        if (L < NLAYERS - 1)
            k_norm<<<((NN + 1) * 16 + 255) / 256, 256, 0, stream>>>(Q, sL, P);
        else
            k_final<<<(NN * 16 + 255) / 256, 256, 0, stream>>>(Q, sL, out);
    }
}

// Round 8
// 640.756 us; speedup vs baseline: 1.2195x; 1.2195x over previous
//
#include <hip/hip_runtime.h>

#define NN 100000
#define NE 1600000
#define NLAYERS 5
#define GIN_EPSF 0.5f
#define BN_EPSF 1e-5f
#define NB 391                 // ceil(NN/256) buckets of 256 nodes
#define CAPR 4608              // raw edges capacity per bucket (mean 4096 + 8 sigma)
#define GRID_L 2048
#define NWAVES (GRID_L * 4)
#define SRCCAP 2250000         // padded srcList ints (E[8*ceil(deg/8)]*NN ~ 1.93M)

typedef unsigned short bfu;
typedef unsigned short u16x4 __attribute__((ext_vector_type(4)));
typedef float f32x4 __attribute__((ext_vector_type(4)));

__device__ inline float bf2f(bfu u) {
    unsigned x = ((unsigned)u) << 16;
    return __builtin_bit_cast(float, x);
}
__device__ inline bfu f2bf(float f) {
    unsigned x = __builtin_bit_cast(unsigned, f);
    unsigned r = (x + 0x7FFF + ((x >> 16) & 1)) >> 16;
    return (bfu)r;
}
__device__ inline f32x4 cvt4(u16x4 v) {
    f32x4 r;
    r.x = bf2f(v.x); r.y = bf2f(v.y); r.z = bf2f(v.z); r.w = bf2f(v.w);
    return r;
}

// tabs layout (ints): [0]=Kc [1]=TotC [2+k]=cls_m [66+k]=cls_nodeBase
// [130+k]=cls_chunkBase (sentinel at Kc) [200+m]=bym_nodeBase [264+m]=bym_chunkBase
// All "chunk" units = 8 padded edges.

// ---------------- embedding gather -> bf16 h0 (+ zero dummy row NN) ----------------
__global__ __launch_bounds__(256) void k_embed(const int* __restrict__ x,
                                               const float* __restrict__ table,
                                               bfu* __restrict__ P) {
    int idx = blockIdx.x * 256 + threadIdx.x;
    if (idx >= (NN + 1) * 16) return;
    int i = idx >> 4, fq = idx & 15;
    u16x4 o = {0, 0, 0, 0};
    if (i < NN) {
        f32x4 v = *(const f32x4*)(table + x[2 * i] * 64 + fq * 4);
        o.x = f2bf(v.x); o.y = f2bf(v.y); o.z = f2bf(v.z); o.w = f2bf(v.w);
    }
    *(u16x4*)(P + (size_t)i * 64 + fq * 4) = o;
}

// ---------------- partition edges into fixed-capacity bucket windows ----------------
__global__ __launch_bounds__(256) void k_part(const int* __restrict__ src,
                                              const int* __restrict__ dst,
                                              int* __restrict__ bcnt,
                                              int* __restrict__ tmp) {
    __shared__ int h[NB];
    __shared__ int hb[NB];
    int t = threadIdx.x;
    for (int k = t; k < NB; k += 256) h[k] = 0;
    __syncthreads();
    int base = blockIdx.x * 2048;
    int v_[8], b_[8], r_[8];
#pragma unroll
    for (int u = 0; u < 8; ++u) {
        int e = base + u * 256 + t;
        if (e < NE) {
            int d = dst[e];
            b_[u] = d >> 8;
            v_[u] = src[e] | ((d & 255) << 20);
            r_[u] = atomicAdd(&h[b_[u]], 1);
        } else {
            b_[u] = -1;
        }
    }
    __syncthreads();
    for (int k = t; k < NB; k += 256)
        hb[k] = h[k] ? (k * CAPR + atomicAdd(&bcnt[k], h[k])) : 0;
    __syncthreads();
#pragma unroll
    for (int u = 0; u < 8; ++u) {
        if (b_[u] >= 0) tmp[hb[b_[u]] + r_[u]] = v_[u];
    }
}

// ---------------- per-bucket: degree count + per-bucket chunk-class histogram ----------------
__global__ __launch_bounds__(256) void k_cnt(const int* __restrict__ tmp,
                                             const int* __restrict__ bcnt,
                                             int* __restrict__ pk,
                                             int* __restrict__ gbh) {
    __shared__ int cnt[256];
    __shared__ int lbh[64];
    int b = blockIdx.x, t = threadIdx.x;
    int n = bcnt[b];
    const int* w = tmp + (size_t)b * CAPR;
    cnt[t] = 0;
    if (t < 64) lbh[t] = 0;
    __syncthreads();
    for (int k = t; k < n; k += 256) atomicAdd(&cnt[w[k] >> 20], 1);
    __syncthreads();
    int node = b * 256 + t;
    int c = cnt[t];
    int pkv = 0;
    if (node < NN) {
        int m = c ? ((c + 7) >> 3) : 1;      // chunks of 8 (zero-degree: 1 dummy chunk)
        int rl = atomicAdd(&lbh[m], 1);
        pkv = c | (rl << 9) | (m << 17);
    }
    pk[b * 256 + t] = pkv;
    __syncthreads();
    if (t < 64) gbh[b * 64 + t] = lbh[t];
}

// ---------------- global scan: per-class bucket prefixes + class tables ----------------
__global__ void k_scan(const int* __restrict__ gbh, int* __restrict__ gBinBase,
                       int* __restrict__ tabs) {
    __shared__ int tot[64];
    int t = threadIdx.x;   // 64 threads, thread t owns class t
    int run = 0;
    for (int b = 0; b < NB; ++b) {
        int v = gbh[b * 64 + t];
        gBinBase[b * 64 + t] = run;
        run += v;
    }
    tot[t] = run;
    __syncthreads();
    if (t == 0) {
        int K = 0, nb = 0;
        long cb = 0;
        for (int m = 63; m >= 1; --m) {      // descending chunk count
            int cN = tot[m];
            if (!cN) continue;
            tabs[2 + K] = m;
            tabs[66 + K] = nb;
            tabs[130 + K] = (int)cb;
            tabs[200 + m] = nb;
            tabs[264 + m] = (int)cb;
            nb += cN;
            cb += (long)cN * m;
            ++K;
        }
        tabs[130 + K] = (int)cb;             // sentinel
        tabs[0] = K;
        tabs[1] = (int)cb;                   // TotC
    }
}

// ---------------- place: sorted work list + 8-padded srcList ----------------
__global__ __launch_bounds__(256) void k_place(const int* __restrict__ tmp,
                                               const int* __restrict__ bcnt,
                                               const int* __restrict__ pk,
                                               const int* __restrict__ gBinBase,
                                               const int* __restrict__ tabs,
                                               int2* __restrict__ work,
                                               int* __restrict__ srcList) {
    __shared__ int cur[256];
    int b = blockIdx.x, t = threadIdx.x;
    int n = bcnt[b];
    const int* w = tmp + (size_t)b * CAPR;
    int node = b * 256 + t;
    int pkv = pk[b * 256 + t];
    if (node < NN) {
        int c = pkv & 511;
        int rl = (pkv >> 9) & 255;
        int m = pkv >> 17;
        int rank = gBinBase[b * 64 + m] + rl;            // rank within class
        int sp = tabs[200 + m] + rank;                   // global sorted position
        int beg = (tabs[264 + m] + rank * m) * 8;        // int offset into srcList
        work[sp] = make_int2(beg, node | (m << 20));
        cur[t] = beg;
        for (int k = c; k < m * 8; ++k) srcList[beg + k] = NN;   // dummy zero-row
    }
    __syncthreads();
    for (int k = t; k < n; k += 256) {
        int v = w[k];
        int pos = atomicAdd(&cur[v >> 20], 1);
        srcList[pos] = v & 0xFFFFF;
    }
}

// ---------------- equal-chunk wave partition helper ----------------
__device__ inline int rank_of(long T, int Kc, int TotC,
                              const int* s_q, const int* s_nb, const int* s_qb) {
    if (T >= TotC) return NN;
    int i = 0;
    for (int j = 1; j < Kc; ++j)
        if (T >= s_qb[j]) i = j;
    int q = s_q[i];
    return s_nb[i] + (int)((T - s_qb[i] + q - 1) / q);   // first rank starting at/after T
}

// ---------------- fused layer: chunked shfl-broadcast indices, deep row pipeline ----------------
__global__ __launch_bounds__(256, 4) void k_layer(
    const bfu* __restrict__ P, float* __restrict__ Q,
    const int2* __restrict__ work, const int* __restrict__ srcList,
    const int* __restrict__ tabs, float* __restrict__ sums) {
    __shared__ float ssum[64], ssq[64];
    __shared__ int s_q[64], s_nb[64], s_qb[65];
    int t = threadIdx.x;
    if (t < 64) {
        ssum[t] = 0.f; ssq[t] = 0.f;
        s_q[t] = tabs[2 + t];
        s_nb[t] = tabs[66 + t];
    }
    if (t < 65) s_qb[t] = tabs[130 + t];
    __syncthreads();
    int Kc = tabs[0], TotC = tabs[1];
    int wv = blockIdx.x * 4 + (t >> 6);
    long Ts = (long)wv * TotC / NWAVES;
    long Te = (long)(wv + 1) * TotC / NWAVES;
    int n0 = rank_of(Ts, Kc, TotC, s_q, s_nb, s_qb);
    int n1 = rank_of(Te, Kc, TotC, s_q, s_nb, s_qb);
    int lane = t & 63;
    int gb = lane & 48;                   // group base lane within wave
    int grp = (lane >> 4);                // 4 groups of 16 lanes
    int c = t & 15;                       // lane covers features 4c..4c+3
    f32x4 lsum = {0.f, 0.f, 0.f, 0.f};
    f32x4 lsq = {0.f, 0.f, 0.f, 0.f};
    for (int sp = n0 + grp; sp < n1; sp += 4) {
        int2 wk = work[sp];
        int beg = wk.x;
        int node = wk.y & 0xFFFFF;
        int m = wk.y >> 20;
        // cooperative index load: one coalesced dword covers the whole chunk
        int sidx = (c < 8) ? srcList[beg + c] : 0;
        u16x4 selfv = *(const u16x4*)(P + (size_t)node * 64 + c * 4);
        f32x4 r = cvt4(selfv) * GIN_EPSF;
        for (int ch = 0; ch < m; ++ch) {
            int nxt = (c < 8 && ch + 1 < m) ? srcList[beg + (ch + 1) * 8 + c] : 0;
            int j0 = __shfl(sidx, gb + 0);
            int j1 = __shfl(sidx, gb + 1);
            int j2 = __shfl(sidx, gb + 2);
            int j3 = __shfl(sidx, gb + 3);
            int j4 = __shfl(sidx, gb + 4);
            int j5 = __shfl(sidx, gb + 5);
            int j6 = __shfl(sidx, gb + 6);
            int j7 = __shfl(sidx, gb + 7);
            u16x4 a0 = *(const u16x4*)(P + (size_t)j0 * 64 + c * 4);
            u16x4 a1 = *(const u16x4*)(P + (size_t)j1 * 64 + c * 4);
            u16x4 a2 = *(const u16x4*)(P + (size_t)j2 * 64 + c * 4);
            u16x4 a3 = *(const u16x4*)(P + (size_t)j3 * 64 + c * 4);
            u16x4 a4 = *(const u16x4*)(P + (size_t)j4 * 64 + c * 4);
            u16x4 a5 = *(const u16x4*)(P + (size_t)j5 * 64 + c * 4);
            u16x4 a6 = *(const u16x4*)(P + (size_t)j6 * 64 + c * 4);
            u16x4 a7 = *(const u16x4*)(P + (size_t)j7 * 64 + c * 4);
            r += ((cvt4(a0) + cvt4(a1)) + (cvt4(a2) + cvt4(a3))) +
                 ((cvt4(a4) + cvt4(a5)) + (cvt4(a6) + cvt4(a7)));
            sidx = nxt;
        }
        *(f32x4*)(Q + (size_t)node * 64 + c * 4) = r;
        lsum += r;
        lsq += r * r;
    }
    atomicAdd(&ssum[c * 4 + 0], lsum.x);
    atomicAdd(&ssum[c * 4 + 1], lsum.y);
    atomicAdd(&ssum[c * 4 + 2], lsum.z);
    atomicAdd(&ssum[c * 4 + 3], lsum.w);
    atomicAdd(&ssq[c * 4 + 0], lsq.x);
    atomicAdd(&ssq[c * 4 + 1], lsq.y);
    atomicAdd(&ssq[c * 4 + 2], lsq.z);
    atomicAdd(&ssq[c * 4 + 3], lsq.w);
    __syncthreads();
    if (t < 64) {
        atomicAdd(&sums[t], ssum[t]);
        atomicAdd(&sums[64 + t], ssq[t]);
    }
}

// ---------------- normalize agg -> bf16 h (params from sums inline) ----------------
__global__ __launch_bounds__(256) void k_norm(const float* __restrict__ Q,
                                              const float* __restrict__ sums,
                                              bfu* __restrict__ P) {
    __shared__ float prm[128];
    int t = threadIdx.x;
    if (t < 64) {
        float s = sums[t], sq = sums[64 + t];
        float mean = s / (float)NN;
        float var = fmaxf(sq / (float)NN - mean * mean, 0.f);
        prm[t] = rsqrtf(var + BN_EPSF);
        prm[64 + t] = mean;
    }
    __syncthreads();
    int idx = blockIdx.x * 256 + t;
    if (idx >= (NN + 1) * 16) return;
    int i = idx >> 4, fq = idx & 15;
    u16x4 o = {0, 0, 0, 0};
    if (i < NN) {
        f32x4 v = *(const f32x4*)(Q + (size_t)i * 64 + fq * 4);
        o.x = f2bf((v.x - prm[64 + fq * 4 + 0]) * prm[fq * 4 + 0]);
        o.y = f2bf((v.y - prm[64 + fq * 4 + 1]) * prm[fq * 4 + 1]);
        o.z = f2bf((v.z - prm[64 + fq * 4 + 2]) * prm[fq * 4 + 2]);
        o.w = f2bf((v.w - prm[64 + fq * 4 + 3]) * prm[fq * 4 + 3]);
    }
    *(u16x4*)(P + (size_t)i * 64 + fq * 4) = o;
}

// ---------------- final normalize -> fp32 out ----------------
__global__ __launch_bounds__(256) void k_final(const float* __restrict__ Q,
                                               const float* __restrict__ sums,
                                               float* __restrict__ out) {
    __shared__ float prm[128];
    int t = threadIdx.x;
    if (t < 64) {
        float s = sums[t], sq = sums[64 + t];
        float mean = s / (float)NN;
        float var = fmaxf(sq / (float)NN - mean * mean, 0.f);
        prm[t] = rsqrtf(var + BN_EPSF);
        prm[64 + t] = mean;
    }
    __syncthreads();
    int idx = blockIdx.x * 256 + t;
    if (idx >= NN * 16) return;
    int i = idx >> 4, fq = idx & 15;
    f32x4 v = *(const f32x4*)(Q + (size_t)i * 64 + fq * 4);
    f32x4 o;
    o.x = (v.x - prm[64 + fq * 4 + 0]) * prm[fq * 4 + 0];
    o.y = (v.y - prm[64 + fq * 4 + 1]) * prm[fq * 4 + 1];
    o.z = (v.z - prm[64 + fq * 4 + 2]) * prm[fq * 4 + 2];
    o.w = (v.w - prm[64 + fq * 4 + 3]) * prm[fq * 4 + 3];
    *(f32x4*)(out + (size_t)i * 64 + fq * 4) = o;
}

extern "C" void kernel_launch(void* const* d_in, const int* in_sizes, int n_in,
                              void* d_out, int out_size, void* d_ws, size_t ws_size,
                              hipStream_t stream) {
    const int* x = (const int*)d_in[0];          // (NN,2)
    const int* ei = (const int*)d_in[1];         // (2,NE)
    const float* table = (const float*)d_in[2];  // (120,64)
    const int* src = ei;
    const int* dst = ei + NE;
    float* out = (float*)d_out;

    // workspace carve-up (~56 MB)
    bfu* P = (bfu*)d_ws;                                   // (NN+1)*64 bf16
    float* Q = (float*)(P + (size_t)(NN + 1) * 64);        // NN*64 f32
    int* srcList = (int*)(Q + (size_t)NN * 64);            // SRCCAP
    int* tmp = srcList + SRCCAP;                           // NB*CAPR
    int2* work = (int2*)(tmp + (size_t)NB * CAPR);         // NN int2
    int* pk = (int*)(work + NN);                           // NB*256
    int* gBinBase = pk + NB * 256;                         // NB*64
    int* gbh = gBinBase + NB * 64;                         // NB*64
    int* bcnt = gbh + NB * 64;                             // NB
    float* sums = (float*)(bcnt + NB);                     // 5*128
    int* tabs = (int*)(sums + NLAYERS * 128);              // 512

    // zero bcnt + all sums slices in one memset
    hipMemsetAsync(bcnt, 0, (NB + NLAYERS * 128) * sizeof(int), stream);

    k_embed<<<((NN + 1) * 16 + 255) / 256, 256, 0, stream>>>(x, table, P);

    // CSR build: bucket partition -> global chunk-class sort -> 8-padded placement
    const int NPB = (NE + 2047) / 2048;  // 782
    k_part<<<NPB, 256, 0, stream>>>(src, dst, bcnt, tmp);
    k_cnt<<<NB, 256, 0, stream>>>(tmp, bcnt, pk, gbh);
    k_scan<<<1, 64, 0, stream>>>(gbh, gBinBase, tabs);
    k_place<<<NB, 256, 0, stream>>>(tmp, bcnt, pk, gBinBase, tabs, work, srcList);

    // 5 layers
    for (int L = 0; L < NLAYERS; ++L) {
        float* sL = sums + L * 128;
        k_layer<<<GRID_L, 256, 0, stream>>>(P, Q, work, srcList, tabs, sL);
        if (L < NLAYERS - 1)
            k_norm<<<((NN + 1) * 16 + 255) / 256, 256, 0, stream>>>(Q, sL, P);
        else
            k_final<<<(NN * 16 + 255) / 256, 256, 0, stream>>>(Q, sL, out);
    }
}

// Round 10
// 511.657 us; speedup vs baseline: 1.5272x; 1.2523x over previous
//
#include <hip/hip_runtime.h>

#define NN 100000
#define NE 1600000
#define NLAYERS 5
#define BN_EPSF 1e-5f
#define NB 391                 // ceil(NN/256) buckets of 256 nodes
#define CAPR 4608              // raw edges capacity per bucket
#define SRCCAP 2250000         // padded srcList ints (+ slack for over-stage reads)
#define NOCT 12500             // NN / 8 exactly
#define LBLK 768               // gather blocks (3/CU at 48KB LDS)
#define TOTW (LBLK * 4)        // 3072 waves

typedef unsigned short bfu;
typedef unsigned short u16x4 __attribute__((ext_vector_type(4)));
typedef float f32x4v __attribute__((ext_vector_type(4)));

__device__ inline float bf2f(bfu u) {
    unsigned x = ((unsigned)u) << 16;
    return __builtin_bit_cast(float, x);
}
__device__ inline bfu f2bf(float f) {
    unsigned x = __builtin_bit_cast(unsigned, f);
    unsigned r = (x + 0x7FFF + ((x >> 16) & 1)) >> 16;
    return (bfu)r;
}
__device__ inline f32x4v cvt4(u16x4 v) {
    f32x4v r;
    r.x = bf2f(v.x); r.y = bf2f(v.y); r.z = bf2f(v.z); r.w = bf2f(v.w);
    return r;
}
__device__ inline void acc8(uint4 d, f32x4v& aL, f32x4v& aH) {
    aL.x += __builtin_bit_cast(float, d.x << 16);
    aL.y += __builtin_bit_cast(float, d.x & 0xFFFF0000u);
    aL.z += __builtin_bit_cast(float, d.y << 16);
    aL.w += __builtin_bit_cast(float, d.y & 0xFFFF0000u);
    aH.x += __builtin_bit_cast(float, d.z << 16);
    aH.y += __builtin_bit_cast(float, d.z & 0xFFFF0000u);
    aH.z += __builtin_bit_cast(float, d.w << 16);
    aH.w += __builtin_bit_cast(float, d.w & 0xFFFF0000u);
}

// async gather-to-LDS: global src per-lane, LDS dest = uniform base + lane*size
#define GLL16(gp, lp) __builtin_amdgcn_global_load_lds( \
    (const __attribute__((address_space(1))) void*)(gp), \
    (__attribute__((address_space(3))) void*)(lp), 16, 0, 0)
#define GLL4(gp, lp) __builtin_amdgcn_global_load_lds( \
    (const __attribute__((address_space(1))) void*)(gp), \
    (__attribute__((address_space(3))) void*)(lp), 4, 0, 0)
#define WAITV0 do { asm volatile("s_waitcnt vmcnt(0)" ::: "memory"); \
                    __builtin_amdgcn_sched_barrier(0); } while (0)

// ---------------- embedding gather -> bf16 h0 (+ zero dummy row NN) ----------------
__global__ __launch_bounds__(256) void k_embed(const int* __restrict__ x,
                                               const float* __restrict__ table,
                                               bfu* __restrict__ P) {
    int idx = blockIdx.x * 256 + threadIdx.x;
    if (idx >= (NN + 1) * 16) return;
    int i = idx >> 4, fq = idx & 15;
    u16x4 o = {0, 0, 0, 0};
    if (i < NN) {
        f32x4v v = *(const f32x4v*)(table + x[2 * i] * 64 + fq * 4);
        o.x = f2bf(v.x); o.y = f2bf(v.y); o.z = f2bf(v.z); o.w = f2bf(v.w);
    }
    *(u16x4*)(P + (size_t)i * 64 + fq * 4) = o;
}

// ---------------- partition edges into fixed-capacity bucket windows ----------------
__global__ __launch_bounds__(256) void k_part(const int* __restrict__ src,
                                              const int* __restrict__ dst,
                                              int* __restrict__ bcnt,
                                              int* __restrict__ tmp) {
    __shared__ int h[NB];
    __shared__ int hb[NB];
    int t = threadIdx.x;
    for (int k = t; k < NB; k += 256) h[k] = 0;
    __syncthreads();
    int base = blockIdx.x * 2048;
    int v_[8], b_[8], r_[8];
#pragma unroll
    for (int u = 0; u < 8; ++u) {
        int e = base + u * 256 + t;
        if (e < NE) {
            int d = dst[e];
            b_[u] = d >> 8;
            v_[u] = src[e] | ((d & 255) << 20);
            r_[u] = atomicAdd(&h[b_[u]], 1);
        } else {
            b_[u] = -1;
        }
    }
    __syncthreads();
    for (int k = t; k < NB; k += 256)
        hb[k] = h[k] ? (k * CAPR + atomicAdd(&bcnt[k], h[k])) : 0;
    __syncthreads();
#pragma unroll
    for (int u = 0; u < 8; ++u) {
        if (b_[u] >= 0) tmp[hb[b_[u]] + r_[u]] = v_[u];
    }
}

// ---------------- per-bucket: degree count + per-bucket chunk-class histogram ----------------
__global__ __launch_bounds__(256) void k_cnt(const int* __restrict__ tmp,
                                             const int* __restrict__ bcnt,
                                             int* __restrict__ pk,
                                             int* __restrict__ gbh) {
    __shared__ int cnt[256];
    __shared__ int lbh[64];
    int b = blockIdx.x, t = threadIdx.x;
    int n = bcnt[b];
    const int* w = tmp + (size_t)b * CAPR;
    cnt[t] = 0;
    if (t < 64) lbh[t] = 0;
    __syncthreads();
    for (int k = t; k < n; k += 256) atomicAdd(&cnt[w[k] >> 20], 1);
    __syncthreads();
    int node = b * 256 + t;
    int c = cnt[t];
    int pkv = 0;
    if (node < NN) {
        int m = c ? ((c + 7) >> 3) : 1;      // chunks of 8 edges
        int rl = atomicAdd(&lbh[m], 1);
        pkv = c | (rl << 9) | (m << 17);
    }
    pk[b * 256 + t] = pkv;
    __syncthreads();
    if (t < 64) gbh[b * 64 + t] = lbh[t];
}

// ---------------- global scan: per-class bucket prefixes + class tables ----------------
__global__ void k_scan(const int* __restrict__ gbh, int* __restrict__ gBinBase,
                       int* __restrict__ tabs) {
    __shared__ int tot[64];
    int t = threadIdx.x;
    int run = 0;
    for (int b = 0; b < NB; ++b) {
        int v = gbh[b * 64 + t];
        gBinBase[b * 64 + t] = run;
        run += v;
    }
    tot[t] = run;
    __syncthreads();
    if (t == 0) {
        int nb = 0;
        long cb = 0;
        for (int m = 63; m >= 1; --m) {      // descending chunk count
            int cN = tot[m];
            if (!cN) continue;
            tabs[200 + m] = nb;
            tabs[264 + m] = (int)cb;
            nb += cN;
            cb += (long)cN * m;
        }
    }
}

// ---------------- place: sorted work list + 8-padded srcList ----------------
__global__ __launch_bounds__(256) void k_place(const int* __restrict__ tmp,
                                               const int* __restrict__ bcnt,
                                               const int* __restrict__ pk,
                                               const int* __restrict__ gBinBase,
                                               const int* __restrict__ tabs,
                                               int2* __restrict__ work,
                                               int* __restrict__ srcList) {
    __shared__ int cur[256];
    int b = blockIdx.x, t = threadIdx.x;
    int n = bcnt[b];
    const int* w = tmp + (size_t)b * CAPR;
    int node = b * 256 + t;
    int pkv = pk[b * 256 + t];
    if (node < NN) {
        int c = pkv & 511;
        int rl = (pkv >> 9) & 255;
        int m = pkv >> 17;
        int rank = gBinBase[b * 64 + m] + rl;
        int sp = tabs[200 + m] + rank;
        int beg = (tabs[264 + m] + rank * m) * 8;
        work[sp] = make_int2(beg, node | (m << 20));
        cur[t] = beg;
        for (int k = c; k < m * 8; ++k) srcList[beg + k] = NN;   // dummy zero-row
    }
    __syncthreads();
    for (int k = t; k < n; k += 256) {
        int v = w[k];
        int pos = atomicAdd(&cur[v >> 20], 1);
        srcList[pos] = v & 0xFFFFF;
    }
}

// ---------------- gather kernel: octet-per-wave, LDS-staged rows via global_load_lds ----------------
__global__ __launch_bounds__(256) void k_gather(
    const bfu* __restrict__ P, float* __restrict__ Q,
    const int2* __restrict__ work, const int* __restrict__ srcList) {
    __shared__ uint4 rows[4][8][64];      // [wave][gather-slot][lane] = 8KB/wave
    __shared__ int idxb[4][2][8][64];     // [wave][parity][window][lane] = 4KB/wave
    int t = threadIdx.x;
    int ws = t >> 6, l = t & 63;
    int g = l >> 3, sl = l & 7;
    int oct = blockIdx.x * 4 + ws;
    if (oct >= NOCT) return;

    // first octet's work entries + params
    int2 wcur = make_int2(0, 0);
    if (l < 8) wcur = work[(size_t)oct * 8 + l];
    int bg = __shfl(wcur.x, g);
    int wy = __shfl(wcur.y, g);
    int node = wy & 0xFFFFF;
    int mg = wy >> 20;
    int mr = (l < 8) ? (wcur.y >> 20) : 0;
    mr = max(mr, __shfl_xor(mr, 1));
    mr = max(mr, __shfl_xor(mr, 2));
    mr = max(mr, __shfl_xor(mr, 4));
    int mMax = __shfl(mr, 0);
    int par = 0;
    if (mMax <= 8) {
        for (int w = 0; w < mMax; ++w)
            GLL4(srcList + bg + w * 8 + sl, &idxb[ws][0][w][0]);
    }
    WAITV0;

    for (;;) {
        int nxt = oct + TOTW;
        f32x4v aL = {0.f, 0.f, 0.f, 0.f}, aH = {0.f, 0.f, 0.f, 0.f};
        int bgN = 0, nodeN = 0, mgN = 0, mMaxN = 0;
        if (mMax <= 8) {
            for (int w = 0; w < mMax; ++w) {
                bool last = (w == mMax - 1);
                int2 wnx = make_int2(0, 0);
                if (last && l < 8 && nxt < NOCT) wnx = work[(size_t)nxt * 8 + l];
                int sj[8];
#pragma unroll
                for (int j = 0; j < 8; ++j) sj[j] = idxb[ws][par][w][g * 8 + j];
#pragma unroll
                for (int j = 0; j < 8; ++j) {
                    int e = w * 8 + j;
                    int idv = (e < (mg << 3)) ? sj[j] : NN;
                    GLL16(P + (size_t)idv * 64 + sl * 8, &rows[ws][j][0]);
                }
                if (last) {
                    bgN = __shfl(wnx.x, g);
                    int wyN = __shfl(wnx.y, g);
                    nodeN = wyN & 0xFFFFF;
                    mgN = wyN >> 20;
                    int mrN = (l < 8) ? (wnx.y >> 20) : 0;
                    mrN = max(mrN, __shfl_xor(mrN, 1));
                    mrN = max(mrN, __shfl_xor(mrN, 2));
                    mrN = max(mrN, __shfl_xor(mrN, 4));
                    mMaxN = __shfl(mrN, 0);
                    if (nxt < NOCT && mMaxN <= 8) {
                        for (int w2 = 0; w2 < mMaxN; ++w2)
                            GLL4(srcList + bgN + w2 * 8 + sl, &idxb[ws][par ^ 1][w2][0]);
                    }
                }
                WAITV0;
#pragma unroll
                for (int j = 0; j < 8; ++j) acc8(rows[ws][j][l], aL, aH);
            }
        } else {
            // rare fallback: octet with deg > 64 node
            int2 wnx = make_int2(0, 0);
            if (l < 8 && nxt < NOCT) wnx = work[(size_t)nxt * 8 + l];
            bgN = __shfl(wnx.x, g);
            int wyN = __shfl(wnx.y, g);
            nodeN = wyN & 0xFFFFF;
            mgN = wyN >> 20;
            int mrN = (l < 8) ? (wnx.y >> 20) : 0;
            mrN = max(mrN, __shfl_xor(mrN, 1));
            mrN = max(mrN, __shfl_xor(mrN, 2));
            mrN = max(mrN, __shfl_xor(mrN, 4));
            mMaxN = __shfl(mrN, 0);
            if (nxt < NOCT && mMaxN <= 8) {
                for (int w2 = 0; w2 < mMaxN; ++w2)
                    GLL4(srcList + bgN + w2 * 8 + sl, &idxb[ws][par ^ 1][w2][0]);
            }
            WAITV0;
            for (int e = 0; e < (mg << 3); ++e) {
                int idv = srcList[bg + e];
                acc8(*(const uint4*)(P + (size_t)idv * 64 + sl * 8), aL, aH);
            }
        }
        float* qr = Q + (size_t)node * 64 + sl * 8;
        *(f32x4v*)qr = aL;
        *(f32x4v*)(qr + 4) = aH;
        if (nxt >= NOCT) break;
        oct = nxt; bg = bgN; node = nodeN; mg = mgN; mMax = mMaxN; par ^= 1;
    }
}

// ---------------- stats pass: agg = Q + 0.5*P, accumulate per-feature sums ----------------
__global__ __launch_bounds__(256) void k_stat(const float* __restrict__ Q,
                                              const bfu* __restrict__ P,
                                              float* __restrict__ sums) {
    __shared__ float ss[64], sq2[64];
    int t = threadIdx.x;
    if (t < 64) { ss[t] = 0.f; sq2[t] = 0.f; }
    __syncthreads();
    int fq = t & 15;
    f32x4v ls = {0.f, 0.f, 0.f, 0.f}, lq = {0.f, 0.f, 0.f, 0.f};
    for (int idx = blockIdx.x * 256 + t; idx < NN * 16; idx += 1024 * 256) {
        int i = idx >> 4;
        f32x4v q = *(const f32x4v*)(Q + (size_t)i * 64 + fq * 4);
        u16x4 p = *(const u16x4*)(P + (size_t)i * 64 + fq * 4);
        f32x4v a = q + cvt4(p) * 0.5f;
        ls += a;
        lq += a * a;
    }
    atomicAdd(&ss[fq * 4 + 0], ls.x);
    atomicAdd(&ss[fq * 4 + 1], ls.y);
    atomicAdd(&ss[fq * 4 + 2], ls.z);
    atomicAdd(&ss[fq * 4 + 3], ls.w);
    atomicAdd(&sq2[fq * 4 + 0], lq.x);
    atomicAdd(&sq2[fq * 4 + 1], lq.y);
    atomicAdd(&sq2[fq * 4 + 2], lq.z);
    atomicAdd(&sq2[fq * 4 + 3], lq.w);
    __syncthreads();
    if (t < 64) {
        atomicAdd(&sums[t], ss[t]);
        atomicAdd(&sums[64 + t], sq2[t]);
    }
}

// ---------------- normalize agg -> bf16 h ----------------
__global__ __launch_bounds__(256) void k_norm(const float* __restrict__ Q,
                                              const float* __restrict__ sums,
                                              bfu* __restrict__ P) {
    __shared__ float prm[128];
    int t = threadIdx.x;
    if (t < 64) {
        float s = sums[t], q2 = sums[64 + t];
        float mean = s / (float)NN;
        float var = fmaxf(q2 / (float)NN - mean * mean, 0.f);
        prm[t] = rsqrtf(var + BN_EPSF);
        prm[64 + t] = mean;
    }
    __syncthreads();
    int idx = blockIdx.x * 256 + t;
    if (idx >= NN * 16) return;
    int i = idx >> 4, fq = idx & 15;
    f32x4v q = *(const f32x4v*)(Q + (size_t)i * 64 + fq * 4);
    u16x4 p = *(const u16x4*)(P + (size_t)i * 64 + fq * 4);
    f32x4v a = q + cvt4(p) * 0.5f;
    u16x4 o;
    o.x = f2bf((a.x - prm[64 + fq * 4 + 0]) * prm[fq * 4 + 0]);
    o.y = f2bf((a.y - prm[64 + fq * 4 + 1]) * prm[fq * 4 + 1]);
    o.z = f2bf((a.z - prm[64 + fq * 4 + 2]) * prm[fq * 4 + 2]);
    o.w = f2bf((a.w - prm[64 + fq * 4 + 3]) * prm[fq * 4 + 3]);
    *(u16x4*)(P + (size_t)i * 64 + fq * 4) = o;
}

// ---------------- final: normalize agg -> fp32 out ----------------
__global__ __launch_bounds__(256) void k_final(const float* __restrict__ Q,
                                               const bfu* __restrict__ P,
                                               const float* __restrict__ sums,
                                               float* __restrict__ out) {
    __shared__ float prm[128];
    int t = threadIdx.x;
    if (t < 64) {
        float s = sums[t], q2 = sums[64 + t];
        float mean = s / (float)NN;
        float var = fmaxf(q2 / (float)NN - mean * mean, 0.f);
        prm[t] = rsqrtf(var + BN_EPSF);
        prm[64 + t] = mean;
    }
    __syncthreads();
    int idx = blockIdx.x * 256 + t;
    if (idx >= NN * 16) return;
    int i = idx >> 4, fq = idx & 15;
    f32x4v q = *(const f32x4v*)(Q + (size_t)i * 64 + fq * 4);
    u16x4 p = *(const u16x4*)(P + (size_t)i * 64 + fq * 4);
    f32x4v a = q + cvt4(p) * 0.5f;
    f32x4v o;
    o.x = (a.x - prm[64 + fq * 4 + 0]) * prm[fq * 4 + 0];
    o.y = (a.y - prm[64 + fq * 4 + 1]) * prm[fq * 4 + 1];
    o.z = (a.z - prm[64 + fq * 4 + 2]) * prm[fq * 4 + 2];
    o.w = (a.w - prm[64 + fq * 4 + 3]) * prm[fq * 4 + 3];
    *(f32x4v*)(out + (size_t)i * 64 + fq * 4) = o;
}

extern "C" void kernel_launch(void* const* d_in, const int* in_sizes, int n_in,
                              void* d_out, int out_size, void* d_ws, size_t ws_size,
                              hipStream_t stream) {
    const int* x = (const int*)d_in[0];          // (NN,2)
    const int* ei = (const int*)d_in[1];         // (2,NE)
    const float* table = (const float*)d_in[2];  // (120,64)
    const int* src = ei;
    const int* dst = ei + NE;
    float* out = (float*)d_out;

    // workspace carve-up (~56 MB)
    bfu* P = (bfu*)d_ws;                                   // (NN+1)*64 bf16
    float* Q = (float*)(P + (size_t)(NN + 1) * 64);        // NN*64 f32
    int* srcList = (int*)(Q + (size_t)NN * 64);            // SRCCAP
    int* tmp = srcList + SRCCAP;                           // NB*CAPR
    int2* work = (int2*)(tmp + (size_t)NB * CAPR);         // NN int2
    int* pk = (int*)(work + NN);                           // NB*256
    int* gBinBase = pk + NB * 256;                         // NB*64
    int* gbh = gBinBase + NB * 64;                         // NB*64
    int* bcnt = gbh + NB * 64;                             // NB
    float* sums = (float*)(bcnt + NB);                     // 5*128
    int* tabs = (int*)(sums + NLAYERS * 128);              // 512

    hipMemsetAsync(bcnt, 0, (NB + NLAYERS * 128) * sizeof(int), stream);

    k_embed<<<((NN + 1) * 16 + 255) / 256, 256, 0, stream>>>(x, table, P);

    // CSR build: bucket partition -> global chunk-class sort -> 8-padded placement
    const int NPB = (NE + 2047) / 2048;  // 782
    k_part<<<NPB, 256, 0, stream>>>(src, dst, bcnt, tmp);
    k_cnt<<<NB, 256, 0, stream>>>(tmp, bcnt, pk, gbh);
    k_scan<<<1, 64, 0, stream>>>(gbh, gBinBase, tabs);
    k_place<<<NB, 256, 0, stream>>>(tmp, bcnt, pk, gBinBase, tabs, work, srcList);

    // 5 layers: gather (pure neighbor sum) -> stats -> normalize
    for (int L = 0; L < NLAYERS; ++L) {
        float* sL = sums + L * 128;
        k_gather<<<LBLK, 256, 0, stream>>>(P, Q, work, srcList);
        k_stat<<<1024, 256, 0, stream>>>(Q, P, sL);
        if (L < NLAYERS - 1)
            k_norm<<<(NN * 16 + 255) / 256, 256, 0, stream>>>(Q, sL, P);
        else
            k_final<<<(NN * 16 + 255) / 256, 256, 0, stream>>>(Q, P, sL, out);
    }
}

// Round 11
// 397.418 us; speedup vs baseline: 1.9662x; 1.2875x over previous
//
#include <hip/hip_runtime.h>

#define NN 100000
#define NE 1600000
#define NLAYERS 5
#define BN_EPSF 1e-5f
#define NB 391                 // ceil(NN/256) buckets of 256 nodes
#define CAPR 4608              // raw edges capacity per bucket
#define SRCCAP 2250000         // padded srcList ints (+ slack for over-stage reads)
#define NOCT 12500             // NN / 8 exactly
#define LBLK 768               // gather blocks (3/CU at 48KB LDS)
#define TOTW (LBLK * 4)        // 3072 waves

typedef unsigned short bfu;
typedef unsigned short u16x4 __attribute__((ext_vector_type(4)));
typedef float f32x4v __attribute__((ext_vector_type(4)));

__device__ inline float bf2f(bfu u) {
    unsigned x = ((unsigned)u) << 16;
    return __builtin_bit_cast(float, x);
}
__device__ inline bfu f2bf(float f) {
    unsigned x = __builtin_bit_cast(unsigned, f);
    unsigned r = (x + 0x7FFF + ((x >> 16) & 1)) >> 16;
    return (bfu)r;
}
__device__ inline f32x4v cvt4(u16x4 v) {
    f32x4v r;
    r.x = bf2f(v.x); r.y = bf2f(v.y); r.z = bf2f(v.z); r.w = bf2f(v.w);
    return r;
}
__device__ inline void acc8(uint4 d, f32x4v& aL, f32x4v& aH) {
    aL.x += __builtin_bit_cast(float, d.x << 16);
    aL.y += __builtin_bit_cast(float, d.x & 0xFFFF0000u);
    aL.z += __builtin_bit_cast(float, d.y << 16);
    aL.w += __builtin_bit_cast(float, d.y & 0xFFFF0000u);
    aH.x += __builtin_bit_cast(float, d.z << 16);
    aH.y += __builtin_bit_cast(float, d.z & 0xFFFF0000u);
    aH.z += __builtin_bit_cast(float, d.w << 16);
    aH.w += __builtin_bit_cast(float, d.w & 0xFFFF0000u);
}

// async gather-to-LDS: global src per-lane, LDS dest = uniform base + lane*size
#define GLL16(gp, lp) __builtin_amdgcn_global_load_lds( \
    (const __attribute__((address_space(1))) void*)(gp), \
    (__attribute__((address_space(3))) void*)(lp), 16, 0, 0)
#define GLL4(gp, lp) __builtin_amdgcn_global_load_lds( \
    (const __attribute__((address_space(1))) void*)(gp), \
    (__attribute__((address_space(3))) void*)(lp), 4, 0, 0)
#define WAITV0 do { asm volatile("s_waitcnt vmcnt(0)" ::: "memory"); \
                    __builtin_amdgcn_sched_barrier(0); } while (0)

// ---------------- embedding gather -> bf16 h0 (+ zero dummy row NN) ----------------
__global__ __launch_bounds__(256) void k_embed(const int* __restrict__ x,
                                               const float* __restrict__ table,
                                               bfu* __restrict__ P) {
    int idx = blockIdx.x * 256 + threadIdx.x;
    if (idx >= (NN + 1) * 16) return;
    int i = idx >> 4, fq = idx & 15;
    u16x4 o = {0, 0, 0, 0};
    if (i < NN) {
        f32x4v v = *(const f32x4v*)(table + x[2 * i] * 64 + fq * 4);
        o.x = f2bf(v.x); o.y = f2bf(v.y); o.z = f2bf(v.z); o.w = f2bf(v.w);
    }
    *(u16x4*)(P + (size_t)i * 64 + fq * 4) = o;
}

// ---------------- partition edges into fixed-capacity bucket windows ----------------
__global__ __launch_bounds__(256) void k_part(const int* __restrict__ src,
                                              const int* __restrict__ dst,
                                              int* __restrict__ bcnt,
                                              int* __restrict__ tmp) {
    __shared__ int h[NB];
    __shared__ int hb[NB];
    int t = threadIdx.x;
    for (int k = t; k < NB; k += 256) h[k] = 0;
    __syncthreads();
    int base = blockIdx.x * 2048;
    int v_[8], b_[8], r_[8];
#pragma unroll
    for (int u = 0; u < 8; ++u) {
        int e = base + u * 256 + t;
        if (e < NE) {
            int d = dst[e];
            b_[u] = d >> 8;
            v_[u] = src[e] | ((d & 255) << 20);
            r_[u] = atomicAdd(&h[b_[u]], 1);
        } else {
            b_[u] = -1;
        }
    }
    __syncthreads();
    for (int k = t; k < NB; k += 256)
        hb[k] = h[k] ? (k * CAPR + atomicAdd(&bcnt[k], h[k])) : 0;
    __syncthreads();
#pragma unroll
    for (int u = 0; u < 8; ++u) {
        if (b_[u] >= 0) tmp[hb[b_[u]] + r_[u]] = v_[u];
    }
}

// ---------------- per-bucket: degree count + per-bucket chunk-class histogram ----------------
__global__ __launch_bounds__(256) void k_cnt(const int* __restrict__ tmp,
                                             const int* __restrict__ bcnt,
                                             int* __restrict__ pk,
                                             int* __restrict__ gbh) {
    __shared__ int cnt[256];
    __shared__ int lbh[64];
    int b = blockIdx.x, t = threadIdx.x;
    int n = bcnt[b];
    const int* w = tmp + (size_t)b * CAPR;
    cnt[t] = 0;
    if (t < 64) lbh[t] = 0;
    __syncthreads();
    for (int k = t; k < n; k += 256) atomicAdd(&cnt[w[k] >> 20], 1);
    __syncthreads();
    int node = b * 256 + t;
    int c = cnt[t];
    int pkv = 0;
    if (node < NN) {
        int m = c ? ((c + 7) >> 3) : 1;      // chunks of 8 edges
        int rl = atomicAdd(&lbh[m], 1);
        pkv = c | (rl << 9) | (m << 17);
    }
    pk[b * 256 + t] = pkv;
    __syncthreads();
    if (t < 64) gbh[b * 64 + t] = lbh[t];
}

// ---------------- global scan: per-class bucket prefixes + class tables ----------------
__global__ void k_scan(const int* __restrict__ gbh, int* __restrict__ gBinBase,
                       int* __restrict__ tabs) {
    __shared__ int tot[64];
    int t = threadIdx.x;
    int run = 0;
    for (int b = 0; b < NB; ++b) {
        int v = gbh[b * 64 + t];
        gBinBase[b * 64 + t] = run;
        run += v;
    }
    tot[t] = run;
    __syncthreads();
    if (t == 0) {
        int nb = 0;
        long cb = 0;
        for (int m = 63; m >= 1; --m) {      // descending chunk count
            int cN = tot[m];
            if (!cN) continue;
            tabs[200 + m] = nb;
            tabs[264 + m] = (int)cb;
            nb += cN;
            cb += (long)cN * m;
        }
    }
}

// ---------------- place: sorted work list + 8-padded srcList ----------------
__global__ __launch_bounds__(256) void k_place(const int* __restrict__ tmp,
                                               const int* __restrict__ bcnt,
                                               const int* __restrict__ pk,
                                               const int* __restrict__ gBinBase,
                                               const int* __restrict__ tabs,
                                               int2* __restrict__ work,
                                               int* __restrict__ srcList) {
    __shared__ int cur[256];
    int b = blockIdx.x, t = threadIdx.x;
    int n = bcnt[b];
    const int* w = tmp + (size_t)b * CAPR;
    int node = b * 256 + t;
    int pkv = pk[b * 256 + t];
    if (node < NN) {
        int c = pkv & 511;
        int rl = (pkv >> 9) & 255;
        int m = pkv >> 17;
        int rank = gBinBase[b * 64 + m] + rl;
        int sp = tabs[200 + m] + rank;
        int beg = (tabs[264 + m] + rank * m) * 8;
        work[sp] = make_int2(beg, node | (m << 20));
        cur[t] = beg;
        for (int k = c; k < m * 8; ++k) srcList[beg + k] = NN;   // dummy zero-row
    }
    __syncthreads();
    for (int k = t; k < n; k += 256) {
        int v = w[k];
        int pos = atomicAdd(&cur[v >> 20], 1);
        srcList[pos] = v & 0xFFFFF;
    }
}

// ---------------- gather kernel: octet-per-wave + fused self-term & stats ----------------
__global__ __launch_bounds__(256) void k_gather(
    const bfu* __restrict__ P, float* __restrict__ Q,
    const int2* __restrict__ work, const int* __restrict__ srcList,
    float* __restrict__ partial) {
    __shared__ uint4 rows[4][8][64];      // [wave][gather-slot][lane] = 8KB/wave
    __shared__ int idxb[4][2][8][64];     // [wave][parity][window][lane] = 4KB/wave
    __shared__ float bsum[64], bsq[64];
    int t = threadIdx.x;
    int ws = t >> 6, l = t & 63;
    int g = l >> 3, sl = l & 7;
    if (t < 64) { bsum[t] = 0.f; bsq[t] = 0.f; }
    __syncthreads();
    int oct = blockIdx.x * 4 + ws;

    f32x4v lsumL = {0.f, 0.f, 0.f, 0.f}, lsumH = {0.f, 0.f, 0.f, 0.f};
    f32x4v lsqL = {0.f, 0.f, 0.f, 0.f}, lsqH = {0.f, 0.f, 0.f, 0.f};

    // first octet's work entries + params
    int2 wcur = make_int2(0, 0);
    if (l < 8) wcur = work[(size_t)oct * 8 + l];
    int bg = __shfl(wcur.x, g);
    int wy = __shfl(wcur.y, g);
    int node = wy & 0xFFFFF;
    int mg = wy >> 20;
    int mr = (l < 8) ? (wcur.y >> 20) : 0;
    mr = max(mr, __shfl_xor(mr, 1));
    mr = max(mr, __shfl_xor(mr, 2));
    mr = max(mr, __shfl_xor(mr, 4));
    int mMax = __shfl(mr, 0);
    int par = 0;
    if (mMax <= 8) {
        for (int w = 0; w < mMax; ++w)
            GLL4(srcList + bg + w * 8 + sl, &idxb[ws][0][w][0]);
    }
    WAITV0;

    for (;;) {
        int nxt = oct + TOTW;
        f32x4v aL = {0.f, 0.f, 0.f, 0.f}, aH = {0.f, 0.f, 0.f, 0.f};
        int bgN = 0, nodeN = 0, mgN = 0, mMaxN = 0;
        uint4 selfr = *(const uint4*)(P + (size_t)node * 64 + sl * 8);
        if (mMax <= 8) {
            for (int w = 0; w < mMax; ++w) {
                bool last = (w == mMax - 1);
                int2 wnx = make_int2(0, 0);
                if (last && l < 8 && nxt < NOCT) wnx = work[(size_t)nxt * 8 + l];
                int sj[8];
#pragma unroll
                for (int j = 0; j < 8; ++j) sj[j] = idxb[ws][par][w][g * 8 + j];
#pragma unroll
                for (int j = 0; j < 8; ++j) {
                    int e = w * 8 + j;
                    int idv = (e < (mg << 3)) ? sj[j] : NN;
                    GLL16(P + (size_t)idv * 64 + sl * 8, &rows[ws][j][0]);
                }
                if (last) {
                    bgN = __shfl(wnx.x, g);
                    int wyN = __shfl(wnx.y, g);
                    nodeN = wyN & 0xFFFFF;
                    mgN = wyN >> 20;
                    int mrN = (l < 8) ? (wnx.y >> 20) : 0;
                    mrN = max(mrN, __shfl_xor(mrN, 1));
                    mrN = max(mrN, __shfl_xor(mrN, 2));
                    mrN = max(mrN, __shfl_xor(mrN, 4));
                    mMaxN = __shfl(mrN, 0);
                    if (nxt < NOCT && mMaxN <= 8) {
                        for (int w2 = 0; w2 < mMaxN; ++w2)
                            GLL4(srcList + bgN + w2 * 8 + sl, &idxb[ws][par ^ 1][w2][0]);
                    }
                }
                WAITV0;
#pragma unroll
                for (int j = 0; j < 8; ++j) acc8(rows[ws][j][l], aL, aH);
            }
        } else {
            // rare fallback: octet with deg > 64 node
            int2 wnx = make_int2(0, 0);
            if (l < 8 && nxt < NOCT) wnx = work[(size_t)nxt * 8 + l];
            bgN = __shfl(wnx.x, g);
            int wyN = __shfl(wnx.y, g);
            nodeN = wyN & 0xFFFFF;
            mgN = wyN >> 20;
            int mrN = (l < 8) ? (wnx.y >> 20) : 0;
            mrN = max(mrN, __shfl_xor(mrN, 1));
            mrN = max(mrN, __shfl_xor(mrN, 2));
            mrN = max(mrN, __shfl_xor(mrN, 4));
            mMaxN = __shfl(mrN, 0);
            if (nxt < NOCT && mMaxN <= 8) {
                for (int w2 = 0; w2 < mMaxN; ++w2)
                    GLL4(srcList + bgN + w2 * 8 + sl, &idxb[ws][par ^ 1][w2][0]);
            }
            WAITV0;
            for (int e = 0; e < (mg << 3); ++e) {
                int idv = srcList[bg + e];
                acc8(*(const uint4*)(P + (size_t)idv * 64 + sl * 8), aL, aH);
            }
        }
        // fused self-term: a = gather + 0.5 * P[node]
        {
            f32x4v z = {0.f, 0.f, 0.f, 0.f};
            f32x4v sLo = z, sHi = z;
            acc8(selfr, sLo, sHi);
            aL += sLo * 0.5f;
            aH += sHi * 0.5f;
        }
        float* qr = Q + (size_t)node * 64 + sl * 8;
        *(f32x4v*)qr = aL;
        *(f32x4v*)(qr + 4) = aH;
        lsumL += aL; lsumH += aH;
        lsqL += aL * aL; lsqH += aH * aH;
        if (nxt >= NOCT) break;
        oct = nxt; bg = bgN; node = nodeN; mg = mgN; mMax = mMaxN; par ^= 1;
    }

    // butterfly-reduce stats across the 8 groups (lanes with same sl)
#pragma unroll
    for (int mask = 8; mask <= 32; mask <<= 1) {
#pragma unroll
        for (int j = 0; j < 4; ++j) {
            lsumL[j] += __shfl_xor(lsumL[j], mask);
            lsumH[j] += __shfl_xor(lsumH[j], mask);
            lsqL[j] += __shfl_xor(lsqL[j], mask);
            lsqH[j] += __shfl_xor(lsqH[j], mask);
        }
    }
    if (g == 0) {
#pragma unroll
        for (int j = 0; j < 4; ++j) {
            atomicAdd(&bsum[sl * 8 + j], lsumL[j]);
            atomicAdd(&bsum[sl * 8 + 4 + j], lsumH[j]);
            atomicAdd(&bsq[sl * 8 + j], lsqL[j]);
            atomicAdd(&bsq[sl * 8 + 4 + j], lsqH[j]);
        }
    }
    __syncthreads();
    if (t < 64) {
        partial[(size_t)blockIdx.x * 128 + t] = bsum[t];
        partial[(size_t)blockIdx.x * 128 + 64 + t] = bsq[t];
    }
}

// ---------------- reduce per-block partials -> sums (no global atomics) ----------------
__global__ void k_red(const float* __restrict__ partial, float* __restrict__ sums) {
    int t = threadIdx.x;   // 128
    float s = 0.f;
    for (int b = 0; b < LBLK; ++b) s += partial[(size_t)b * 128 + t];
    sums[t] = s;
}

// ---------------- normalize agg(Q) -> bf16 h ----------------
__global__ __launch_bounds__(256) void k_norm(const float* __restrict__ Q,
                                              const float* __restrict__ sums,
                                              bfu* __restrict__ P) {
    __shared__ float prm[128];
    int t = threadIdx.x;
    if (t < 64) {
        float s = sums[t], q2 = sums[64 + t];
        float mean = s / (float)NN;
        float var = fmaxf(q2 / (float)NN - mean * mean, 0.f);
        prm[t] = rsqrtf(var + BN_EPSF);
        prm[64 + t] = mean;
    }
    __syncthreads();
    int idx = blockIdx.x * 256 + t;
    if (idx >= NN * 16) return;
    int i = idx >> 4, fq = idx & 15;
    f32x4v a = *(const f32x4v*)(Q + (size_t)i * 64 + fq * 4);
    u16x4 o;
    o.x = f2bf((a.x - prm[64 + fq * 4 + 0]) * prm[fq * 4 + 0]);
    o.y = f2bf((a.y - prm[64 + fq * 4 + 1]) * prm[fq * 4 + 1]);
    o.z = f2bf((a.z - prm[64 + fq * 4 + 2]) * prm[fq * 4 + 2]);
    o.w = f2bf((a.w - prm[64 + fq * 4 + 3]) * prm[fq * 4 + 3]);
    *(u16x4*)(P + (size_t)i * 64 + fq * 4) = o;
}

// ---------------- final: normalize agg(Q) -> fp32 out ----------------
__global__ __launch_bounds__(256) void k_final(const float* __restrict__ Q,
                                               const float* __restrict__ sums,
                                               float* __restrict__ out) {
    __shared__ float prm[128];
    int t = threadIdx.x;
    if (t < 64) {
        float s = sums[t], q2 = sums[64 + t];
        float mean = s / (float)NN;
        float var = fmaxf(q2 / (float)NN - mean * mean, 0.f);
        prm[t] = rsqrtf(var + BN_EPSF);
        prm[64 + t] = mean;
    }
    __syncthreads();
    int idx = blockIdx.x * 256 + t;
    if (idx >= NN * 16) return;
    int i = idx >> 4, fq = idx & 15;
    f32x4v a = *(const f32x4v*)(Q + (size_t)i * 64 + fq * 4);
    f32x4v o;
    o.x = (a.x - prm[64 + fq * 4 + 0]) * prm[fq * 4 + 0];
    o.y = (a.y - prm[64 + fq * 4 + 1]) * prm[fq * 4 + 1];
    o.z = (a.z - prm[64 + fq * 4 + 2]) * prm[fq * 4 + 2];
    o.w = (a.w - prm[64 + fq * 4 + 3]) * prm[fq * 4 + 3];
    *(f32x4v*)(out + (size_t)i * 64 + fq * 4) = o;
}

extern "C" void kernel_launch(void* const* d_in, const int* in_sizes, int n_in,
                              void* d_out, int out_size, void* d_ws, size_t ws_size,
                              hipStream_t stream) {
    const int* x = (const int*)d_in[0];          // (NN,2)
    const int* ei = (const int*)d_in[1];         // (2,NE)
    const float* table = (const float*)d_in[2];  // (120,64)
    const int* src = ei;
    const int* dst = ei + NE;
    float* out = (float*)d_out;

    // workspace carve-up (~57 MB)
    bfu* P = (bfu*)d_ws;                                   // (NN+1)*64 bf16
    float* Q = (float*)(P + (size_t)(NN + 1) * 64);        // NN*64 f32
    int* srcList = (int*)(Q + (size_t)NN * 64);            // SRCCAP
    int* tmp = srcList + SRCCAP;                           // NB*CAPR
    int2* work = (int2*)(tmp + (size_t)NB * CAPR);         // NN int2
    int* pk = (int*)(work + NN);                           // NB*256
    int* gBinBase = pk + NB * 256;                         // NB*64
    int* gbh = gBinBase + NB * 64;                         // NB*64
    int* bcnt = gbh + NB * 64;                             // NB
    float* partial = (float*)(bcnt + NB);                  // LBLK*128
    float* sums = partial + (size_t)LBLK * 128;            // 128
    int* tabs = (int*)(sums + 128);                        // 512

    hipMemsetAsync(bcnt, 0, NB * sizeof(int), stream);

    k_embed<<<((NN + 1) * 16 + 255) / 256, 256, 0, stream>>>(x, table, P);

    // CSR build: bucket partition -> global chunk-class sort -> 8-padded placement
    const int NPB = (NE + 2047) / 2048;  // 782
    k_part<<<NPB, 256, 0, stream>>>(src, dst, bcnt, tmp);
    k_cnt<<<NB, 256, 0, stream>>>(tmp, bcnt, pk, gbh);
    k_scan<<<1, 64, 0, stream>>>(gbh, gBinBase, tabs);
    k_place<<<NB, 256, 0, stream>>>(tmp, bcnt, pk, gBinBase, tabs, work, srcList);

    // 5 layers: gather(+self+stats) -> reduce -> normalize
    for (int L = 0; L < NLAYERS; ++L) {
        k_gather<<<LBLK, 256, 0, stream>>>(P, Q, work, srcList, partial);
        k_red<<<1, 128, 0, stream>>>(partial, sums);
        if (L < NLAYERS - 1)
            k_norm<<<(NN * 16 + 255) / 256, 256, 0, stream>>>(Q, sums, P);
        else
            k_final<<<(NN * 16 + 255) / 256, 256, 0, stream>>>(Q, sums, out);
    }
}